// Round 2
// baseline (3792.305 us; speedup 1.0000x reference)
//
#include <hip/hip_runtime.h>

#define HW 65536          // 256*256
#define NPOS 262144       // B(4) * HW

typedef unsigned int   u32;
typedef unsigned short u16;

__device__ __forceinline__ float bf2f(u16 h){
  union { u32 u; float f; } c; c.u = ((u32)h) << 16; return c.f;
}
__device__ __forceinline__ u16 f2bf(float f){
  union { u32 u; float f; } c; c.f = f;
  u32 r = c.u + 0x7fffu + ((c.u >> 16) & 1u);   // round-nearest-even
  return (u16)(r >> 16);
}
__device__ __forceinline__ float gelu_exact(float x){
  return 0.5f*x*(1.0f+erff(x*0.70710678118654752f));
}

// ---------------- K0: per-channel spatial kernel g from fft_param mask ----------------
// g_c[u,v] = (1/64) * sum_{k1,k2 in 0..7} S[k1,k2] cos(2pi (k1 u + k2 v)/8)
// S[k1,k2] = M[k1,k2] (k2<=4), else M[(8-k1)&7, 8-k2]   (M real)
__global__ void k_build_g(const float* __restrict__ M, float* __restrict__ g){
  int t = blockIdx.x*blockDim.x + threadIdx.x;
  if (t >= 256*64) return;
  int c = t >> 6, uv = t & 63, u = uv >> 3, v = uv & 7;
  const float* mc = M + c*40;
  const float ctab[8] = {1.f, 0.70710678118654752f, 0.f, -0.70710678118654752f,
                         -1.f, -0.70710678118654752f, 0.f, 0.70710678118654752f};
  float acc = 0.f;
  for (int k1=0;k1<8;k1++){
    for (int k2=0;k2<8;k2++){
      float s = (k2<=4) ? mc[k1*5+k2] : mc[(((8-k1)&7)*5) + (8-k2)];
      acc += s * ctab[(k1*u + k2*v)&7];
    }
  }
  g[t] = acc * (1.f/64.f);
}

// ---------------- fused channel-LN (C=64) + conv1x1 chunk (64 out rows), fp32 src -> bf16 dst ----------------
__global__ __launch_bounds__(256) void k_ln_conv64(
    const float* __restrict__ src, const float* __restrict__ lnw, const float* __restrict__ lnb,
    const float* __restrict__ Wm, int o0, u16* __restrict__ dst)
{
  int p = blockIdx.x*256 + threadIdx.x;
  int b = p >> 16, hw = p & 65535;
  const float* sp = src + (size_t)b*64*HW + hw;
  float s[64];
  float mean = 0.f;
  #pragma unroll
  for (int c=0;c<64;c++){ s[c] = sp[(size_t)c*HW]; mean += s[c]; }
  mean *= (1.f/64.f);
  float var = 0.f;
  #pragma unroll
  for (int c=0;c<64;c++){ float d = s[c]-mean; var += d*d; }
  float inv = rsqrtf(var*(1.f/64.f) + 1e-5f);
  #pragma unroll
  for (int c=0;c<64;c++) s[c] = (s[c]-mean)*inv*lnw[c] + lnb[c];
  u16* dp = dst + (size_t)b*64*HW + hw;
  #pragma unroll 4
  for (int o=0;o<64;o++){
    const float* wr = Wm + (size_t)(o0+o)*64;
    float acc = 0.f;
    #pragma unroll
    for (int c=0;c<64;c++) acc += s[c]*wr[c];
    dp[(size_t)o*HW] = f2bf(acc);
  }
}

// ---------------- depthwise 3x3, zero pad, bf16 -> bf16 ----------------
__global__ __launch_bounds__(256) void k_dw(
    const u16* __restrict__ src, const float* __restrict__ wgt, int c0,
    u16* __restrict__ dst, int dstC, int dstOff)
{
  int idx = blockIdx.x*256 + threadIdx.x;     // < 4*64*HW
  int w = idx & 255, h = (idx>>8)&255, c = (idx>>16)&63, b = idx>>22;
  const float* wp = wgt + (size_t)(c0+c)*9;
  const u16* spl = src + ((size_t)(b*64+c))*HW;
  float acc = 0.f;
  #pragma unroll
  for (int dy=-1;dy<=1;dy++){
    int hh = h+dy; if (hh<0 || hh>255) continue;
    #pragma unroll
    for (int dx=-1;dx<=1;dx++){
      int ww = w+dx; if (ww<0 || ww>255) continue;
      acc += bf2f(spl[hh*256+ww]) * wp[(dy+1)*3+(dx+1)];
    }
  }
  dst[((size_t)(b*dstC + dstOff + c))*HW + h*256 + w] = f2bf(acc);
}

// ---------------- patch helpers ----------------
__device__ __forceinline__ void load_patch_bf(const u16* p, float v[8][8]){
  #pragma unroll
  for (int r=0;r<8;r++){
    uint4 u = *(const uint4*)(p + (size_t)r*256);
    v[r][0]=bf2f((u16)(u.x&0xffff)); v[r][1]=bf2f((u16)(u.x>>16));
    v[r][2]=bf2f((u16)(u.y&0xffff)); v[r][3]=bf2f((u16)(u.y>>16));
    v[r][4]=bf2f((u16)(u.z&0xffff)); v[r][5]=bf2f((u16)(u.z>>16));
    v[r][6]=bf2f((u16)(u.w&0xffff)); v[r][7]=bf2f((u16)(u.w>>16));
  }
}

// dw 3x3 of one 8x8 patch with image-global zero padding, bf16 plane -> f32 regs
__device__ __forceinline__ void dw_patch(const u16* __restrict__ plane, const float* __restrict__ w9,
                                         int h0, int w0, float out[8][8])
{
  float win[10][10];
  #pragma unroll
  for (int r=0;r<10;r++){
    int h = h0-1+r;
    bool hv = (h>=0 && h<256);
    #pragma unroll
    for (int j=0;j<10;j++){
      int w = w0-1+j;
      win[r][j] = (hv && w>=0 && w<256) ? bf2f(plane[h*256+w]) : 0.f;
    }
  }
  float w00=w9[0],w01=w9[1],w02=w9[2],w10=w9[3],w11=w9[4],w12=w9[5],w20=w9[6],w21=w9[7],w22=w9[8];
  #pragma unroll
  for (int i=0;i<8;i++)
    #pragma unroll
    for (int j=0;j<8;j++)
      out[i][j] = win[i  ][j]*w00 + win[i  ][j+1]*w01 + win[i  ][j+2]*w02
                + win[i+1][j]*w10 + win[i+1][j+1]*w11 + win[i+1][j+2]*w12
                + win[i+2][j]*w20 + win[i+2][j+1]*w21 + win[i+2][j+2]*w22;
}

// 8x8 circular conv o = q (circ*) k, store bf16 rows (uint4 each)
__device__ __forceinline__ void circ_store_bf(const float q[8][8], const float k[8][8], u16* op){
  #pragma unroll
  for (int i=0;i<8;i++){
    float o[8] = {0,0,0,0,0,0,0,0};
    #pragma unroll
    for (int u=0;u<8;u++){
      #pragma unroll
      for (int v=0;v<8;v++){
        float qq = q[u][v];
        #pragma unroll
        for (int j=0;j<8;j++) o[j] += qq * k[(i-u)&7][(j-v)&7];
      }
    }
    uint4 pk;
    pk.x = (u32)f2bf(o[0]) | ((u32)f2bf(o[1])<<16);
    pk.y = (u32)f2bf(o[2]) | ((u32)f2bf(o[3])<<16);
    pk.z = (u32)f2bf(o[4]) | ((u32)f2bf(o[5])<<16);
    pk.w = (u32)f2bf(o[6]) | ((u32)f2bf(o[7])<<16);
    *(uint4*)(op + (size_t)i*256) = pk;
  }
}

// ---------------- fused dw3x3(q), dw3x3(k), then per-patch circular conv -> oraw bf16 ----------------
// grid (16, 64, 4), block 64
__global__ __launch_bounds__(64) void k_circqk_dw(
    const u16* __restrict__ bq, const u16* __restrict__ bk,
    const float* __restrict__ dwq, const float* __restrict__ dwk, int c0,
    u16* __restrict__ oraw, int oc0)
{
  int tid = threadIdx.x;
  int px = tid & 31, py = blockIdx.x*2 + (tid>>5);
  int c = blockIdx.y, b = blockIdx.z;
  int h0 = py*8, w0 = px*8;
  const u16* qp = bq + ((size_t)(b*64+c))*HW;
  const u16* kp = bk + ((size_t)(b*64+c))*HW;
  float qv[8][8], kv[8][8];
  dw_patch(qp, dwq + (size_t)(c0+c)*9, h0, w0, qv);
  dw_patch(kp, dwk + (size_t)(c0+c)*9, h0, w0, kv);
  u16* op = oraw + ((size_t)(b*128 + oc0 + c))*HW + (size_t)h0*256 + w0;
  circ_store_bf(qv, kv, op);
}

// ---------------- DFFN spectral circular conv with per-channel kernel g, IN-PLACE on bf16 chunk ----------------
__global__ __launch_bounds__(64) void k_circg(
    u16* __restrict__ y, const float* __restrict__ g, int gc0)
{
  int tid = threadIdx.x;
  int px = tid & 31, py = blockIdx.x*2 + (tid>>5);
  int c = blockIdx.y, b = blockIdx.z;
  u16* p = y + ((size_t)(b*64+c))*HW + (size_t)py*8*256 + (size_t)px*8;
  float yv[8][8], kv[8][8];
  load_patch_bf(p, yv);
  const float* gp = g + (size_t)(gc0 + c)*64;
  #pragma unroll
  for (int r=0;r<8;r++)
    #pragma unroll
    for (int j=0;j<8;j++) kv[r][j] = gp[r*8+j];
  circ_store_bf(yv, kv, p);   // in-place: this thread owns the whole patch
}

// ---------------- attn epilogue: x2 = x + conv1x1( v * LN_128(oraw), Wpo ) ----------------
__global__ __launch_bounds__(256) void k_attn_out(
    const float* __restrict__ x, const u16* __restrict__ oraw, const u16* __restrict__ v,
    const float* __restrict__ lnw, const float* __restrict__ lnb,
    const float* __restrict__ Wpo, float* __restrict__ x2)
{
  int p = blockIdx.x*256 + threadIdx.x;
  int b = p >> 16, hw = p & 65535;
  const u16* op_ = oraw + (size_t)b*128*HW + hw;
  float t[128];
  float mean = 0.f;
  #pragma unroll
  for (int c=0;c<128;c++){ t[c] = bf2f(op_[(size_t)c*HW]); mean += t[c]; }
  mean *= (1.f/128.f);
  float var = 0.f;
  #pragma unroll
  for (int c=0;c<128;c++){ float d = t[c]-mean; var += d*d; }
  float inv = rsqrtf(var*(1.f/128.f) + 1e-5f);
  const u16* vp = v + (size_t)b*128*HW + hw;
  #pragma unroll
  for (int c=0;c<128;c++) t[c] = ((t[c]-mean)*inv*lnw[c] + lnb[c]) * bf2f(vp[(size_t)c*HW]);
  const float* xp = x + (size_t)b*64*HW + hw;
  float* dp = x2 + (size_t)b*64*HW + hw;
  #pragma unroll 4
  for (int o=0;o<64;o++){
    const float* wr = Wpo + (size_t)o*128;
    float acc = 0.f;
    #pragma unroll
    for (int c=0;c<128;c++) acc += t[c]*wr[c];
    dp[(size_t)o*HW] = xp[(size_t)o*HW] + acc;
  }
}

// ---------------- ffn epilogue: out = x2 + conv1x1( gelu(y3[:128]) * y3[128:], Wpo ) ----------------
__global__ __launch_bounds__(256) void k_ffn_out(
    const u16* __restrict__ y3, const float* __restrict__ Wpo, float* __restrict__ xo)
{
  int p = blockIdx.x*256 + threadIdx.x;
  int b = p >> 16, hw = p & 65535;
  const u16* yp = y3 + (size_t)b*256*HW + hw;
  float t[128];
  #pragma unroll
  for (int c=0;c<128;c++){
    float a  = bf2f(yp[(size_t)c*HW]);
    float bb = bf2f(yp[(size_t)(c+128)*HW]);
    t[c] = gelu_exact(a) * bb;
  }
  float* xp = xo + (size_t)b*64*HW + hw;
  #pragma unroll 4
  for (int o=0;o<64;o++){
    const float* wr = Wpo + (size_t)o*128;
    float acc = 0.f;
    #pragma unroll
    for (int c=0;c<128;c++) acc += t[c]*wr[c];
    xp[(size_t)o*HW] = xp[(size_t)o*HW] + acc;   // read-then-write by same thread: safe in-place
  }
}

extern "C" void kernel_launch(void* const* d_in, const int* in_sizes, int n_in,
                              void* d_out, int out_size, void* d_ws, size_t ws_size,
                              hipStream_t stream)
{
  const float* x       = (const float*)d_in[0];
  const float* evt     = (const float*)d_in[1];
  const float* ln1i_w  = (const float*)d_in[2];
  const float* ln1i_b  = (const float*)d_in[3];
  const float* ln1e_w  = (const float*)d_in[4];
  const float* ln1e_b  = (const float*)d_in[5];
  const float* w_q     = (const float*)d_in[6];
  const float* dw_q    = (const float*)d_in[7];
  const float* w_kv    = (const float*)d_in[8];
  const float* dw_kv   = (const float*)d_in[9];
  const float* lnA_w   = (const float*)d_in[10];
  const float* lnA_b   = (const float*)d_in[11];
  const float* w_po_at = (const float*)d_in[12];
  const float* ln2_w   = (const float*)d_in[13];
  const float* ln2_b   = (const float*)d_in[14];
  const float* w_pi    = (const float*)d_in[15];
  const float* fft_par = (const float*)d_in[16];
  const float* dw_ffn  = (const float*)d_in[17];
  const float* w_poffn = (const float*)d_in[18];
  float* out = (float*)d_out;

  char* ws = (char*)d_ws;
  // compact bf16 arena — peak 160 MiB + 64 KiB:
  u16* oraw = (u16*)(ws);                        // 64 MiB  (B,128,HW) bf16
  u16* bq   = (u16*)(ws +  67108864ull);         // 32 MiB  (B,64,HW)
  u16* bk   = (u16*)(ws + 100663296ull);         // 32 MiB
  u16* vbuf = (u16*)(ws +  67108864ull);         // 64 MiB  (B,128,HW) — reuses bq+bk (dead)
  u16* tmpC = (u16*)(ws + 134217728ull);         // 32 MiB  chunk (B,64,HW)
  u16* y3   = (u16*)(ws);                        // 128 MiB (B,256,HW) — reuses oraw+vbuf (dead)
  float* gbuf = (float*)(ws + 167772160ull);     // 64 KiB  (256,8,8)

  dim3 blk256(256), blk64(64);
  dim3 gPos(NPOS/256);                 // 1024
  dim3 gDw(4*64*HW/256);               // 65536
  dim3 gPatch(16, 64, 4);

  k_build_g<<<64, blk256, 0, stream>>>(fft_par, gbuf);

  // ---- attention q,k chunks: LN+conv1x1 -> (dw3x3 fused) patch circular conv ----
  for (int i=0;i<2;i++){
    k_ln_conv64<<<gPos, blk256, 0, stream>>>(x,   ln1i_w, ln1i_b, w_q,  64*i, bq);
    k_ln_conv64<<<gPos, blk256, 0, stream>>>(evt, ln1e_w, ln1e_b, w_kv, 64*i, bk);
    k_circqk_dw<<<gPatch, blk64, 0, stream>>>(bq, bk, dw_q, dw_kv, 64*i, oraw, 64*i);
  }
  // ---- v chunks ----
  for (int i=0;i<2;i++){
    k_ln_conv64<<<gPos, blk256, 0, stream>>>(evt, ln1e_w, ln1e_b, w_kv, 128+64*i, tmpC);
    k_dw<<<gDw, blk256, 0, stream>>>(tmpC, dw_kv, 128+64*i, vbuf, 128, 64*i);
  }
  // ---- attn epilogue -> x2 in d_out ----
  k_attn_out<<<gPos, blk256, 0, stream>>>(x, oraw, vbuf, lnA_w, lnA_b, w_po_at, out);

  // ---- DFFN ----
  for (int j=0;j<4;j++){
    k_ln_conv64<<<gPos, blk256, 0, stream>>>(out, ln2_w, ln2_b, w_pi, 64*j, tmpC);
    k_circg<<<gPatch, blk64, 0, stream>>>(tmpC, gbuf, 64*j);
    k_dw<<<gDw, blk256, 0, stream>>>(tmpC, dw_ffn, 64*j, y3, 256, 64*j);
  }
  k_ffn_out<<<gPos, blk256, 0, stream>>>(y3, w_poffn, out);
}

// Round 3
// 1805.685 us; speedup vs baseline: 2.1002x; 2.1002x over previous
//
#include <hip/hip_runtime.h>

#define HW 65536          // 256*256
#define NPOS 262144       // B(4) * HW

typedef unsigned int   u32;
typedef unsigned short u16;
typedef __attribute__((ext_vector_type(8))) short v8s;
typedef __attribute__((ext_vector_type(4))) float f32x4;

__device__ __forceinline__ float bf2f(u16 h){
  union { u32 u; float f; } c; c.u = ((u32)h) << 16; return c.f;
}
__device__ __forceinline__ u16 f2bf(float f){
  union { u32 u; float f; } c; c.f = f;
  u32 r = c.u + 0x7fffu + ((c.u >> 16) & 1u);   // round-nearest-even
  return (u16)(r >> 16);
}
__device__ __forceinline__ u32 pk2(float a, float b){
  return (u32)f2bf(a) | ((u32)f2bf(b) << 16);
}
__device__ __forceinline__ v8s as8(uint4 u){
  union { uint4 a; v8s b; } c; c.a = u; return c.b;
}
__device__ __forceinline__ float gelu_exact(float x){
  return 0.5f*x*(1.0f+erff(x*0.70710678118654752f));
}

// ---------------- K0: per-channel spatial kernel g from fft_param mask ----------------
__global__ void k_build_g(const float* __restrict__ M, float* __restrict__ g){
  int t = blockIdx.x*blockDim.x + threadIdx.x;
  if (t >= 256*64) return;
  int c = t >> 6, uv = t & 63, u = uv >> 3, v = uv & 7;
  const float* mc = M + c*40;
  const float ctab[8] = {1.f, 0.70710678118654752f, 0.f, -0.70710678118654752f,
                         -1.f, -0.70710678118654752f, 0.f, 0.70710678118654752f};
  float acc = 0.f;
  for (int k1=0;k1<8;k1++){
    for (int k2=0;k2<8;k2++){
      float s = (k2<=4) ? mc[k1*5+k2] : mc[(((8-k1)&7)*5) + (8-k2)];
      acc += s * ctab[(k1*u + k2*v)&7];
    }
  }
  g[t] = acc * (1.f/64.f);
}

// ================= MFMA GEMM kernels =================
// Block: 256 thr (4 waves) handles 256 pixels x 64 outputs.
// A (M=out, K) = weights bf16 in LDS; B (K, N=pix) = staged activations bf16 in LDS.
// D[out][pix]: lane l reg j -> out = po*16 + (l>>4)*4 + j, pix = pp*16 + (l&15).

// ---- LN(C=64) + conv1x1 (64 out rows) -> bf16 planar chunk (B,64,HW) ----
__global__ __launch_bounds__(256) void k_gemm_ln(
    const float* __restrict__ src, const float* __restrict__ lnw, const float* __restrict__ lnb,
    const float* __restrict__ W, int o0, u16* __restrict__ dst)
{
  __shared__ uint4 lsX[256*8];   // 32KB: 256 rows x 8 slots (K=64)
  __shared__ uint4 lsW[64*8];    // 8KB
  int tid = threadIdx.x;
  int pixbase = blockIdx.x*256;
  int b = pixbase >> 16, hwb = pixbase & 65535;

  // stage X = LN(src pixel tid)
  {
    const float* sp = src + (size_t)b*64*HW + (hwb + tid);
    float s[64]; float mean = 0.f;
    #pragma unroll
    for (int c=0;c<64;c++){ s[c] = sp[(size_t)c*HW]; mean += s[c]; }
    mean *= (1.f/64.f);
    float var = 0.f;
    #pragma unroll
    for (int c=0;c<64;c++){ float d = s[c]-mean; var += d*d; }
    float inv = rsqrtf(var*(1.f/64.f) + 1e-5f);
    #pragma unroll
    for (int c=0;c<64;c++) s[c] = (s[c]-mean)*inv*lnw[c] + lnb[c];
    uint4* xrow = lsX + tid*8;
    #pragma unroll
    for (int sl=0; sl<8; sl++){
      uint4 p; p.x = pk2(s[sl*8+0], s[sl*8+1]); p.y = pk2(s[sl*8+2], s[sl*8+3]);
      p.z = pk2(s[sl*8+4], s[sl*8+5]); p.w = pk2(s[sl*8+6], s[sl*8+7]);
      xrow[sl ^ (tid & 7)] = p;
    }
  }
  // stage W (64 x 64 fp32 -> bf16)
  {
    uint2* lw = (uint2*)lsW;
    #pragma unroll
    for (int it=0; it<4; it++){
      int i = it*256 + tid;            // float4 index, 1024 total
      int row = i >> 4, f4c = i & 15;
      float4 f = *(const float4*)(W + (size_t)(o0+row)*64 + f4c*4);
      uint2 h; h.x = pk2(f.x, f.y); h.y = pk2(f.z, f.w);
      int sl = f4c >> 1, sw = sl ^ (row & 7);
      lw[row*16 + sw*2 + (f4c & 1)] = h;
    }
  }
  __syncthreads();

  int w = tid>>6, l = tid&63, g = l>>4, c15 = l&15;
  f32x4 acc[4][4];
  #pragma unroll
  for (int pp=0;pp<4;pp++)
    #pragma unroll
    for (int po=0;po<4;po++) acc[pp][po] = (f32x4){0.f,0.f,0.f,0.f};

  #pragma unroll
  for (int kk=0; kk<2; kk++){
    v8s wf[4], xf[4];
    #pragma unroll
    for (int po=0;po<4;po++){
      int row = po*16 + c15, sl = kk*4 + g;
      wf[po] = as8(lsW[row*8 + (sl ^ (row&7))]);
    }
    #pragma unroll
    for (int pp=0;pp<4;pp++){
      int row = w*64 + pp*16 + c15, sl = kk*4 + g;
      xf[pp] = as8(lsX[row*8 + (sl ^ (row&7))]);
    }
    #pragma unroll
    for (int pp=0;pp<4;pp++)
      #pragma unroll
      for (int po=0;po<4;po++)
        acc[pp][po] = __builtin_amdgcn_mfma_f32_16x16x32_bf16(wf[po], xf[pp], acc[pp][po], 0,0,0);
  }
  // store bf16 planar chunk-local (B,64,HW)
  size_t obase = (size_t)b*64*HW + hwb + w*64;
  #pragma unroll
  for (int po=0;po<4;po++)
    #pragma unroll
    for (int j=0;j<4;j++){
      int oc = po*16 + g*4 + j;
      u16* dp = dst + obase + (size_t)oc*HW + c15;
      #pragma unroll
      for (int pp=0;pp<4;pp++) dp[pp*16] = f2bf(acc[pp][po][j]);
    }
}

// ---- attn epilogue: d_out = x + W(64x128) * (v .* LN128(oraw)) ----
__global__ __launch_bounds__(256) void k_gemm_attn(
    const float* __restrict__ x, const u16* __restrict__ oraw, const u16* __restrict__ vb,
    const float* __restrict__ lnw, const float* __restrict__ lnb,
    const float* __restrict__ W, float* __restrict__ out)
{
  __shared__ uint4 lsX[256*16];  // 64KB (K=128)
  __shared__ uint4 lsW[64*16];   // 16KB
  int tid = threadIdx.x;
  int pixbase = blockIdx.x*256;
  int b = pixbase >> 16, hwb = pixbase & 65535;
  {
    const u16* op_ = oraw + (size_t)b*128*HW + (hwb + tid);
    const u16* vp  = vb   + (size_t)b*128*HW + (hwb + tid);
    float t[128]; float mean = 0.f;
    #pragma unroll
    for (int c=0;c<128;c++){ t[c] = bf2f(op_[(size_t)c*HW]); mean += t[c]; }
    mean *= (1.f/128.f);
    float var = 0.f;
    #pragma unroll
    for (int c=0;c<128;c++){ float d = t[c]-mean; var += d*d; }
    float inv = rsqrtf(var*(1.f/128.f) + 1e-5f);
    #pragma unroll
    for (int c=0;c<128;c++) t[c] = ((t[c]-mean)*inv*lnw[c] + lnb[c]) * bf2f(vp[(size_t)c*HW]);
    uint4* xrow = lsX + tid*16;
    #pragma unroll
    for (int sl=0; sl<16; sl++){
      uint4 p; p.x = pk2(t[sl*8+0], t[sl*8+1]); p.y = pk2(t[sl*8+2], t[sl*8+3]);
      p.z = pk2(t[sl*8+4], t[sl*8+5]); p.w = pk2(t[sl*8+6], t[sl*8+7]);
      xrow[sl ^ (tid & 15)] = p;
    }
  }
  {
    uint2* lw = (uint2*)lsW;
    #pragma unroll
    for (int it=0; it<8; it++){
      int i = it*256 + tid;           // 2048 float4s
      int row = i >> 5, f4c = i & 31;
      float4 f = *(const float4*)(W + (size_t)row*128 + f4c*4);
      uint2 h; h.x = pk2(f.x, f.y); h.y = pk2(f.z, f.w);
      int sl = f4c >> 1, sw = sl ^ (row & 15);
      lw[row*32 + sw*2 + (f4c & 1)] = h;
    }
  }
  __syncthreads();

  int w = tid>>6, l = tid&63, g = l>>4, c15 = l&15;
  f32x4 acc[4][4];
  #pragma unroll
  for (int pp=0;pp<4;pp++)
    #pragma unroll
    for (int po=0;po<4;po++) acc[pp][po] = (f32x4){0.f,0.f,0.f,0.f};

  #pragma unroll
  for (int kk=0; kk<4; kk++){
    v8s wf[4], xf[4];
    #pragma unroll
    for (int po=0;po<4;po++){
      int row = po*16 + c15, sl = kk*4 + g;
      wf[po] = as8(lsW[row*16 + (sl ^ (row&15))]);
    }
    #pragma unroll
    for (int pp=0;pp<4;pp++){
      int row = w*64 + pp*16 + c15, sl = kk*4 + g;
      xf[pp] = as8(lsX[row*16 + (sl ^ (row&15))]);
    }
    #pragma unroll
    for (int pp=0;pp<4;pp++)
      #pragma unroll
      for (int po=0;po<4;po++)
        acc[pp][po] = __builtin_amdgcn_mfma_f32_16x16x32_bf16(wf[po], xf[pp], acc[pp][po], 0,0,0);
  }
  size_t obase = (size_t)b*64*HW + hwb + w*64;
  #pragma unroll
  for (int po=0;po<4;po++)
    #pragma unroll
    for (int j=0;j<4;j++){
      int oc = po*16 + g*4 + j;
      const float* xs = x + obase + (size_t)oc*HW + c15;
      float* dp = out + obase + (size_t)oc*HW + c15;
      #pragma unroll
      for (int pp=0;pp<4;pp++) dp[pp*16] = xs[pp*16] + acc[pp][po][j];
    }
}

// ---- ffn epilogue: d_out += W(64x128) * (gelu(y3[:128]) .* y3[128:]) ----
__global__ __launch_bounds__(256) void k_gemm_ffn(
    const u16* __restrict__ y3, const float* __restrict__ W, float* __restrict__ out)
{
  __shared__ uint4 lsX[256*16];
  __shared__ uint4 lsW[64*16];
  int tid = threadIdx.x;
  int pixbase = blockIdx.x*256;
  int b = pixbase >> 16, hwb = pixbase & 65535;
  {
    const u16* yp = y3 + (size_t)b*256*HW + (hwb + tid);
    float t[128];
    #pragma unroll
    for (int c=0;c<128;c++)
      t[c] = gelu_exact(bf2f(yp[(size_t)c*HW])) * bf2f(yp[(size_t)(c+128)*HW]);
    uint4* xrow = lsX + tid*16;
    #pragma unroll
    for (int sl=0; sl<16; sl++){
      uint4 p; p.x = pk2(t[sl*8+0], t[sl*8+1]); p.y = pk2(t[sl*8+2], t[sl*8+3]);
      p.z = pk2(t[sl*8+4], t[sl*8+5]); p.w = pk2(t[sl*8+6], t[sl*8+7]);
      xrow[sl ^ (tid & 15)] = p;
    }
  }
  {
    uint2* lw = (uint2*)lsW;
    #pragma unroll
    for (int it=0; it<8; it++){
      int i = it*256 + tid;
      int row = i >> 5, f4c = i & 31;
      float4 f = *(const float4*)(W + (size_t)row*128 + f4c*4);
      uint2 h; h.x = pk2(f.x, f.y); h.y = pk2(f.z, f.w);
      int sl = f4c >> 1, sw = sl ^ (row & 15);
      lw[row*32 + sw*2 + (f4c & 1)] = h;
    }
  }
  __syncthreads();

  int w = tid>>6, l = tid&63, g = l>>4, c15 = l&15;
  f32x4 acc[4][4];
  #pragma unroll
  for (int pp=0;pp<4;pp++)
    #pragma unroll
    for (int po=0;po<4;po++) acc[pp][po] = (f32x4){0.f,0.f,0.f,0.f};

  #pragma unroll
  for (int kk=0; kk<4; kk++){
    v8s wf[4], xf[4];
    #pragma unroll
    for (int po=0;po<4;po++){
      int row = po*16 + c15, sl = kk*4 + g;
      wf[po] = as8(lsW[row*16 + (sl ^ (row&15))]);
    }
    #pragma unroll
    for (int pp=0;pp<4;pp++){
      int row = w*64 + pp*16 + c15, sl = kk*4 + g;
      xf[pp] = as8(lsX[row*16 + (sl ^ (row&15))]);
    }
    #pragma unroll
    for (int pp=0;pp<4;pp++)
      #pragma unroll
      for (int po=0;po<4;po++)
        acc[pp][po] = __builtin_amdgcn_mfma_f32_16x16x32_bf16(wf[po], xf[pp], acc[pp][po], 0,0,0);
  }
  size_t obase = (size_t)b*64*HW + hwb + w*64;
  #pragma unroll
  for (int po=0;po<4;po++)
    #pragma unroll
    for (int j=0;j<4;j++){
      int oc = po*16 + g*4 + j;
      float* dp = out + obase + (size_t)oc*HW + c15;
      #pragma unroll
      for (int pp=0;pp<4;pp++) dp[pp*16] = dp[pp*16] + acc[pp][po][j];
    }
}

// ---------------- depthwise 3x3, zero pad, bf16 -> bf16 ----------------
__global__ __launch_bounds__(256) void k_dw(
    const u16* __restrict__ src, const float* __restrict__ wgt, int c0,
    u16* __restrict__ dst, int dstC, int dstOff)
{
  int idx = blockIdx.x*256 + threadIdx.x;     // < 4*64*HW
  int w = idx & 255, h = (idx>>8)&255, c = (idx>>16)&63, b = idx>>22;
  const float* wp = wgt + (size_t)(c0+c)*9;
  const u16* spl = src + ((size_t)(b*64+c))*HW;
  float acc = 0.f;
  #pragma unroll
  for (int dy=-1;dy<=1;dy++){
    int hh = h+dy; if (hh<0 || hh>255) continue;
    #pragma unroll
    for (int dx=-1;dx<=1;dx++){
      int ww = w+dx; if (ww<0 || ww>255) continue;
      acc += bf2f(spl[hh*256+ww]) * wp[(dy+1)*3+(dx+1)];
    }
  }
  dst[((size_t)(b*dstC + dstOff + c))*HW + h*256 + w] = f2bf(acc);
}

// ---------------- patch helpers ----------------
__device__ __forceinline__ void load_patch_bf(const u16* p, float v[8][8]){
  #pragma unroll
  for (int r=0;r<8;r++){
    uint4 u = *(const uint4*)(p + (size_t)r*256);
    v[r][0]=bf2f((u16)(u.x&0xffff)); v[r][1]=bf2f((u16)(u.x>>16));
    v[r][2]=bf2f((u16)(u.y&0xffff)); v[r][3]=bf2f((u16)(u.y>>16));
    v[r][4]=bf2f((u16)(u.z&0xffff)); v[r][5]=bf2f((u16)(u.z>>16));
    v[r][6]=bf2f((u16)(u.w&0xffff)); v[r][7]=bf2f((u16)(u.w>>16));
  }
}

__device__ __forceinline__ void dw_patch(const u16* __restrict__ plane, const float* __restrict__ w9,
                                         int h0, int w0, float out[8][8])
{
  float win[10][10];
  #pragma unroll
  for (int r=0;r<10;r++){
    int h = h0-1+r;
    bool hv = (h>=0 && h<256);
    #pragma unroll
    for (int j=0;j<10;j++){
      int w = w0-1+j;
      win[r][j] = (hv && w>=0 && w<256) ? bf2f(plane[h*256+w]) : 0.f;
    }
  }
  float w00=w9[0],w01=w9[1],w02=w9[2],w10=w9[3],w11=w9[4],w12=w9[5],w20=w9[6],w21=w9[7],w22=w9[8];
  #pragma unroll
  for (int i=0;i<8;i++)
    #pragma unroll
    for (int j=0;j<8;j++)
      out[i][j] = win[i  ][j]*w00 + win[i  ][j+1]*w01 + win[i  ][j+2]*w02
                + win[i+1][j]*w10 + win[i+1][j+1]*w11 + win[i+1][j+2]*w12
                + win[i+2][j]*w20 + win[i+2][j+1]*w21 + win[i+2][j+2]*w22;
}

__device__ __forceinline__ void circ_store_bf(const float q[8][8], const float k[8][8], u16* op){
  #pragma unroll
  for (int i=0;i<8;i++){
    float o[8] = {0,0,0,0,0,0,0,0};
    #pragma unroll
    for (int u=0;u<8;u++){
      #pragma unroll
      for (int v=0;v<8;v++){
        float qq = q[u][v];
        #pragma unroll
        for (int j=0;j<8;j++) o[j] += qq * k[(i-u)&7][(j-v)&7];
      }
    }
    uint4 pk;
    pk.x = (u32)f2bf(o[0]) | ((u32)f2bf(o[1])<<16);
    pk.y = (u32)f2bf(o[2]) | ((u32)f2bf(o[3])<<16);
    pk.z = (u32)f2bf(o[4]) | ((u32)f2bf(o[5])<<16);
    pk.w = (u32)f2bf(o[6]) | ((u32)f2bf(o[7])<<16);
    *(uint4*)(op + (size_t)i*256) = pk;
  }
}

// ---- fused dw3x3(q), dw3x3(k), per-patch circular conv -> oraw bf16 ----
__global__ __launch_bounds__(64) void k_circqk_dw(
    const u16* __restrict__ bq, const u16* __restrict__ bk,
    const float* __restrict__ dwq, const float* __restrict__ dwk, int c0,
    u16* __restrict__ oraw, int oc0)
{
  int tid = threadIdx.x;
  int px = tid & 31, py = blockIdx.x*2 + (tid>>5);
  int c = blockIdx.y, b = blockIdx.z;
  int h0 = py*8, w0 = px*8;
  const u16* qp = bq + ((size_t)(b*64+c))*HW;
  const u16* kp = bk + ((size_t)(b*64+c))*HW;
  float qv[8][8], kv[8][8];
  dw_patch(qp, dwq + (size_t)(c0+c)*9, h0, w0, qv);
  dw_patch(kp, dwk + (size_t)(c0+c)*9, h0, w0, kv);
  u16* op = oraw + ((size_t)(b*128 + oc0 + c))*HW + (size_t)h0*256 + w0;
  circ_store_bf(qv, kv, op);
}

// ---- DFFN spectral circular conv, in-place ----
__global__ __launch_bounds__(64) void k_circg(
    u16* __restrict__ y, const float* __restrict__ g, int gc0)
{
  int tid = threadIdx.x;
  int px = tid & 31, py = blockIdx.x*2 + (tid>>5);
  int c = blockIdx.y, b = blockIdx.z;
  u16* p = y + ((size_t)(b*64+c))*HW + (size_t)py*8*256 + (size_t)px*8;
  float yv[8][8], kv[8][8];
  load_patch_bf(p, yv);
  const float* gp = g + (size_t)(gc0 + c)*64;
  #pragma unroll
  for (int r=0;r<8;r++)
    #pragma unroll
    for (int j=0;j<8;j++) kv[r][j] = gp[r*8+j];
  circ_store_bf(yv, kv, p);
}

extern "C" void kernel_launch(void* const* d_in, const int* in_sizes, int n_in,
                              void* d_out, int out_size, void* d_ws, size_t ws_size,
                              hipStream_t stream)
{
  const float* x       = (const float*)d_in[0];
  const float* evt     = (const float*)d_in[1];
  const float* ln1i_w  = (const float*)d_in[2];
  const float* ln1i_b  = (const float*)d_in[3];
  const float* ln1e_w  = (const float*)d_in[4];
  const float* ln1e_b  = (const float*)d_in[5];
  const float* w_q     = (const float*)d_in[6];
  const float* dw_q    = (const float*)d_in[7];
  const float* w_kv    = (const float*)d_in[8];
  const float* dw_kv   = (const float*)d_in[9];
  const float* lnA_w   = (const float*)d_in[10];
  const float* lnA_b   = (const float*)d_in[11];
  const float* w_po_at = (const float*)d_in[12];
  const float* ln2_w   = (const float*)d_in[13];
  const float* ln2_b   = (const float*)d_in[14];
  const float* w_pi    = (const float*)d_in[15];
  const float* fft_par = (const float*)d_in[16];
  const float* dw_ffn  = (const float*)d_in[17];
  const float* w_poffn = (const float*)d_in[18];
  float* out = (float*)d_out;

  char* ws = (char*)d_ws;
  // arena: peak 160 MiB + 64 KiB (same as round 1, which fit)
  u16* oraw = (u16*)(ws);                        // 64 MiB (B,128,HW)
  u16* P1   = (u16*)(ws +  67108864ull);         // 32 MiB (B,64,HW)
  u16* P2   = (u16*)(ws + 100663296ull);         // 32 MiB
  u16* vbuf = (u16*)(ws + 100663296ull);         // 64 MiB (B,128,HW) — reuses P2 (dead in v phase)
  u16* y3   = (u16*)(ws);                        // 128 MiB (B,256,HW) — reuses oraw/P1/vbuf head
  u16* Ptmp = (u16*)(ws + 134217728ull);         // 32 MiB
  float* gbuf = (float*)(ws + 167772160ull);     // 64 KiB

  dim3 blk256(256), blk64(64);
  dim3 gGemm(NPOS/256);                // 1024
  dim3 gDw(4*64*HW/256);               // 65536
  dim3 gPatch(16, 64, 4);

  k_build_g<<<64, blk256, 0, stream>>>(fft_par, gbuf);

  // ---- attention q,k chunks ----
  for (int i=0;i<2;i++){
    k_gemm_ln<<<gGemm, blk256, 0, stream>>>(x,   ln1i_w, ln1i_b, w_q,  64*i, P1);
    k_gemm_ln<<<gGemm, blk256, 0, stream>>>(evt, ln1e_w, ln1e_b, w_kv, 64*i, P2);
    k_circqk_dw<<<gPatch, blk64, 0, stream>>>(P1, P2, dw_q, dw_kv, 64*i, oraw, 64*i);
  }
  // ---- v chunks ----
  for (int i=0;i<2;i++){
    k_gemm_ln<<<gGemm, blk256, 0, stream>>>(evt, ln1e_w, ln1e_b, w_kv, 128+64*i, P1);
    k_dw<<<gDw, blk256, 0, stream>>>(P1, dw_kv, 128+64*i, vbuf, 128, 64*i);
  }
  // ---- attn epilogue -> d_out ----
  k_gemm_attn<<<gGemm, blk256, 0, stream>>>(x, oraw, vbuf, lnA_w, lnA_b, w_po_at, out);

  // ---- DFFN ----
  for (int j=0;j<4;j++){
    k_gemm_ln<<<gGemm, blk256, 0, stream>>>(out, ln2_w, ln2_b, w_pi, 64*j, Ptmp);
    k_circg<<<gPatch, blk64, 0, stream>>>(Ptmp, gbuf, 64*j);
    k_dw<<<gDw, blk256, 0, stream>>>(Ptmp, dw_ffn, 64*j, y3, 256, 64*j);
  }
  k_gemm_ffn<<<gGemm, blk256, 0, stream>>>(y3, w_poffn, out);
}

// Round 4
// 1404.425 us; speedup vs baseline: 2.7003x; 1.2857x over previous
//
#include <hip/hip_runtime.h>

#define HW 65536          // 256*256
#define NPOS 262144       // B(4) * HW

typedef unsigned int   u32;
typedef unsigned short u16;
typedef __attribute__((ext_vector_type(8))) short v8s;
typedef __attribute__((ext_vector_type(4))) float f32x4;

__device__ __forceinline__ float bf2f(u16 h){
  union { u32 u; float f; } c; c.u = ((u32)h) << 16; return c.f;
}
__device__ __forceinline__ u16 f2bf(float f){
  union { u32 u; float f; } c; c.f = f;
  u32 r = c.u + 0x7fffu + ((c.u >> 16) & 1u);
  return (u16)(r >> 16);
}
__device__ __forceinline__ u32 pk2(float a, float b){
  return (u32)f2bf(a) | ((u32)f2bf(b) << 16);
}
__device__ __forceinline__ v8s as8(uint4 u){
  union { uint4 a; v8s b; } c; c.a = u; return c.b;
}
__device__ __forceinline__ float gelu_exact(float x){
  return 0.5f*x*(1.0f+erff(x*0.70710678118654752f));
}

// ================= prep: spectral kernel g + LN-folded bf16 weights =================
__device__ void fold_w(const float* __restrict__ W, int rows,
                       const float* __restrict__ lw, const float* __restrict__ lb,
                       u16* __restrict__ Wf, float* __restrict__ A, float* __restrict__ B){
  int tid = threadIdx.x;
  for (int e = tid; e < rows*64; e += 256) Wf[e] = f2bf(lw[e & 63] * W[e]);
  for (int r = tid; r < rows; r += 256){
    float a = 0.f, b2 = 0.f;
    for (int c = 0; c < 64; c++){ float w = W[r*64+c]; a += lw[c]*w; b2 += lb[c]*w; }
    A[r] = a; B[r] = b2;
  }
}

__global__ void k_prep(const float* __restrict__ M, float* __restrict__ g,
    const float* wq,  const float* l1iw, const float* l1ib, u16* wqf,  float* aq,  float* bq,
    const float* wkv, const float* l1ew, const float* l1eb, u16* wkvf, float* akv, float* bkv,
    const float* wpi, const float* l2w,  const float* l2b,  u16* wpif, float* api, float* bpi,
    const float* wpa, u16* wpaf, const float* wpf, u16* wpff)
{
  int blk = blockIdx.x, tid = threadIdx.x;
  if (blk < 64){
    int t = blk*256 + tid;           // < 256*64
    int c = t >> 6, uv = t & 63, u = uv >> 3, v = uv & 7;
    const float* mc = M + c*40;
    const float ctab[8] = {1.f, 0.70710678118654752f, 0.f, -0.70710678118654752f,
                           -1.f, -0.70710678118654752f, 0.f, 0.70710678118654752f};
    float acc = 0.f;
    for (int k1=0;k1<8;k1++)
      for (int k2=0;k2<8;k2++){
        float s = (k2<=4) ? mc[k1*5+k2] : mc[(((8-k1)&7)*5) + (8-k2)];
        acc += s * ctab[(k1*u + k2*v)&7];
      }
    g[t] = acc * (1.f/64.f);
  } else if (blk == 64){ fold_w(wq, 128, l1iw, l1ib, wqf, aq, bq); }
  else if (blk == 65){ fold_w(wkv, 256, l1ew, l1eb, wkvf, akv, bkv); }
  else if (blk == 66){ fold_w(wpi, 256, l2w, l2b, wpif, api, bpi); }
  else if (blk == 67){ for (int e=tid; e<64*128; e+=256) wpaf[e] = f2bf(wpa[e]); }
  else               { for (int e=tid; e<64*128; e+=256) wpff[e] = f2bf(wpf[e]); }
}

// ================= per-pixel LN stats (mu, inv) over 64 channels =================
__global__ __launch_bounds__(256) void k_stats(
    const float* __restrict__ s0, float2* __restrict__ d0,
    const float* __restrict__ s1, float2* __restrict__ d1)
{
  const float* src = blockIdx.y ? s1 : s0;
  float2* dst = blockIdx.y ? d1 : d0;
  int p = blockIdx.x*256 + threadIdx.x;
  int b = p >> 16, hw = p & 65535;
  const float* sp = src + (size_t)b*64*HW + hw;
  float s = 0.f, q = 0.f;
  #pragma unroll
  for (int c=0;c<64;c++){ float e = sp[(size_t)c*HW]; s += e; q += e*e; }
  float mu = s*(1.f/64.f);
  float var = q*(1.f/64.f) - mu*mu;
  dst[p] = make_float2(mu, rsqrtf(fmaxf(var,0.f)+1e-5f));
}

// ================= K=64 GEMM with folded LN: dst[o] = inv*(acc - mu*A[o]) + B[o] =================
struct GA {
  const float* src; const float2* st; const u16* Wf; const float* Af; const float* Bf;
  u16* dst; int o0; int dstOff; int Cd; int b0; int pxbase;
};

__global__ __launch_bounds__(256) void k_gemm64(GA a0, GA a1){
  GA a = (blockIdx.y == 0) ? a0 : a1;
  int o0 = a.o0 + 64*blockIdx.z;
  int dstOff = a.dstOff + 64*blockIdx.z;
  __shared__ uint4 lsX[256*8];   // 32KB
  __shared__ uint4 lsW[64*8];    // 8KB
  int tid = threadIdx.x;
  int p0 = a.pxbase + blockIdx.x*256;
  int b = p0 >> 16, hwb = p0 & 65535;
  // stage W'
  {
    const uint4* wsrc = (const uint4*)(a.Wf + (size_t)o0*64);
    #pragma unroll
    for (int i=0;i<2;i++){
      int idx = i*256 + tid, row = idx>>3, s = idx&7;
      lsW[row*8 + (s ^ (row&7))] = wsrc[idx];
    }
  }
  // stage raw X -> bf16
  {
    const float* sp = a.src + (size_t)b*64*HW + hwb + tid;
    uint4* xrow = lsX + tid*8;
    #pragma unroll
    for (int sl=0; sl<8; sl++){
      float e0=sp[(size_t)(sl*8+0)*HW], e1=sp[(size_t)(sl*8+1)*HW];
      float e2=sp[(size_t)(sl*8+2)*HW], e3=sp[(size_t)(sl*8+3)*HW];
      float e4=sp[(size_t)(sl*8+4)*HW], e5=sp[(size_t)(sl*8+5)*HW];
      float e6=sp[(size_t)(sl*8+6)*HW], e7=sp[(size_t)(sl*8+7)*HW];
      uint4 pkv; pkv.x=pk2(e0,e1); pkv.y=pk2(e2,e3); pkv.z=pk2(e4,e5); pkv.w=pk2(e6,e7);
      xrow[sl ^ (tid&7)] = pkv;
    }
  }
  __syncthreads();
  int w = tid>>6, l = tid&63, g = l>>4, c15 = l&15;
  f32x4 acc[4][4];
  #pragma unroll
  for (int pp=0;pp<4;pp++)
    #pragma unroll
    for (int po=0;po<4;po++) acc[pp][po] = (f32x4){0.f,0.f,0.f,0.f};
  #pragma unroll
  for (int kk=0; kk<2; kk++){
    v8s wf[4], xf[4];
    #pragma unroll
    for (int po=0;po<4;po++){ int row = po*16 + c15; wf[po] = as8(lsW[row*8 + ((kk*4+g) ^ (row&7))]); }
    #pragma unroll
    for (int pp=0;pp<4;pp++){ int row = w*64 + pp*16 + c15; xf[pp] = as8(lsX[row*8 + ((kk*4+g) ^ (row&7))]); }
    #pragma unroll
    for (int pp=0;pp<4;pp++)
      #pragma unroll
      for (int po=0;po<4;po++)
        acc[pp][po] = __builtin_amdgcn_mfma_f32_16x16x32_bf16(wf[po], xf[pp], acc[pp][po], 0,0,0);
  }
  float2 stv[4];
  #pragma unroll
  for (int pp=0;pp<4;pp++) stv[pp] = a.st[p0 + w*64 + pp*16 + c15];
  size_t obase = ((size_t)(b - a.b0)*a.Cd + dstOff)*HW + hwb + w*64;
  #pragma unroll
  for (int po=0;po<4;po++)
    #pragma unroll
    for (int j=0;j<4;j++){
      int oc = po*16 + g*4 + j;
      float Ao = a.Af[o0+oc], Bo = a.Bf[o0+oc];
      u16* dp = a.dst + obase + (size_t)oc*HW + c15;
      #pragma unroll
      for (int pp=0;pp<4;pp++)
        dp[pp*16] = f2bf(stv[pp].y*(acc[pp][po][j] - stv[pp].x*Ao) + Bo);
    }
}

// ================= attn epilogue GEMM (K=128): out = x + Wpo * (v .* LN128(oraw)) =================
__global__ __launch_bounds__(256) void k_gemm_attn(
    const float* __restrict__ x, const u16* __restrict__ oraw, const u16* __restrict__ vb,
    const float* __restrict__ lnw, const float* __restrict__ lnb,
    const u16* __restrict__ Wf, float* __restrict__ out)
{
  __shared__ uint4 lsX[128*16];  // 32KB
  __shared__ uint4 lsW[64*16];   // 16KB
  __shared__ float2 sPart[256];
  __shared__ float2 sStat[128];
  int tid = threadIdx.x;
  int p0 = blockIdx.x*128;
  int b = p0 >> 16, hwb = p0 & 65535;
  int px = tid & 127, hf = tid >> 7;
  {
    const uint4* wsrc = (const uint4*)Wf;
    #pragma unroll
    for (int i=0;i<4;i++){
      int idx = i*256 + tid, row = idx>>4, s = idx&15;
      lsW[row*16 + (s ^ (row&15))] = wsrc[idx];
    }
  }
  // phase 1: raw oraw rows into lsX + stats
  const u16* op_ = oraw + ((size_t)b*128 + hf*64)*HW + hwb + px;
  float sum = 0.f, ssq = 0.f;
  #pragma unroll
  for (int sl=0; sl<8; sl++){
    u32 wds[4];
    #pragma unroll
    for (int q2=0;q2<4;q2++){
      u16 lo = op_[(size_t)(sl*8+q2*2  )*HW];
      u16 hi = op_[(size_t)(sl*8+q2*2+1)*HW];
      float fl = bf2f(lo), fh = bf2f(hi);
      sum += fl + fh; ssq += fl*fl + fh*fh;
      wds[q2] = (u32)lo | ((u32)hi << 16);
    }
    int s = hf*8 + sl;
    lsX[px*16 + (s ^ (px&15))] = make_uint4(wds[0],wds[1],wds[2],wds[3]);
  }
  sPart[tid] = make_float2(sum, ssq);
  __syncthreads();
  if (tid < 128){
    float2 A = sPart[tid], B = sPart[tid+128];
    float s = A.x + B.x, q = A.y + B.y;
    float mu = s*(1.f/128.f);
    float var = q*(1.f/128.f) - mu*mu;
    sStat[tid] = make_float2(mu, rsqrtf(fmaxf(var,0.f)+1e-5f));
  }
  __syncthreads();
  // phase 2: LN * v rewrite in place
  float2 st = sStat[px];
  const u16* vp = vb + ((size_t)b*128 + hf*64)*HW + hwb + px;
  #pragma unroll
  for (int sl=0; sl<8; sl++){
    int s = hf*8 + sl;
    int li = px*16 + (s ^ (px&15));
    uint4 raw = lsX[li];
    u32 wds[4] = {raw.x, raw.y, raw.z, raw.w};
    u32 ow[4];
    #pragma unroll
    for (int q2=0;q2<4;q2++){
      int ch = hf*64 + sl*8 + q2*2;
      float e0 = bf2f((u16)(wds[q2]&0xffff)), e1 = bf2f((u16)(wds[q2]>>16));
      float v0 = bf2f(vp[(size_t)(sl*8+q2*2  )*HW]);
      float v1 = bf2f(vp[(size_t)(sl*8+q2*2+1)*HW]);
      float r0 = ((e0-st.x)*st.y*lnw[ch  ] + lnb[ch  ])*v0;
      float r1 = ((e1-st.x)*st.y*lnw[ch+1] + lnb[ch+1])*v1;
      ow[q2] = pk2(r0, r1);
    }
    lsX[li] = make_uint4(ow[0],ow[1],ow[2],ow[3]);
  }
  __syncthreads();
  int w4 = tid>>6, l = tid&63, g = l>>4, c15 = l&15;
  f32x4 acc[2][4];
  #pragma unroll
  for (int pp=0;pp<2;pp++)
    #pragma unroll
    for (int po=0;po<4;po++) acc[pp][po] = (f32x4){0.f,0.f,0.f,0.f};
  #pragma unroll
  for (int kk=0; kk<4; kk++){
    v8s wf[4], xf[2];
    #pragma unroll
    for (int po=0;po<4;po++){ int row = po*16 + c15; wf[po] = as8(lsW[row*16 + ((kk*4+g) ^ (row&15))]); }
    #pragma unroll
    for (int pp=0;pp<2;pp++){ int row = w4*32 + pp*16 + c15; xf[pp] = as8(lsX[row*16 + ((kk*4+g) ^ (row&15))]); }
    #pragma unroll
    for (int pp=0;pp<2;pp++)
      #pragma unroll
      for (int po=0;po<4;po++)
        acc[pp][po] = __builtin_amdgcn_mfma_f32_16x16x32_bf16(wf[po], xf[pp], acc[pp][po], 0,0,0);
  }
  size_t obase = (size_t)b*64*HW + hwb + w4*32;
  #pragma unroll
  for (int po=0;po<4;po++)
    #pragma unroll
    for (int j=0;j<4;j++){
      int oc = po*16 + g*4 + j;
      const float* xs = x + obase + (size_t)oc*HW + c15;
      float* dp = out + obase + (size_t)oc*HW + c15;
      #pragma unroll
      for (int pp=0;pp<2;pp++) dp[pp*16] = xs[pp*16] + acc[pp][po][j];
    }
}

// ================= ffn epilogue GEMM (K=128): out += Wpo * (gelu(y[:128]) .* y[128:]) =================
__global__ __launch_bounds__(256) void k_gemm_ffn(
    const u16* __restrict__ y3, const u16* __restrict__ Wf, float* __restrict__ out,
    int pxbase, int b0)
{
  __shared__ uint4 lsX[128*16];
  __shared__ uint4 lsW[64*16];
  int tid = threadIdx.x;
  int p0 = pxbase + blockIdx.x*128;
  int b = p0 >> 16, hwb = p0 & 65535;
  int px = tid & 127, hf = tid >> 7;
  {
    const uint4* wsrc = (const uint4*)Wf;
    #pragma unroll
    for (int i=0;i<4;i++){
      int idx = i*256 + tid, row = idx>>4, s = idx&15;
      lsW[row*16 + (s ^ (row&15))] = wsrc[idx];
    }
  }
  const u16* yp = y3 + ((size_t)(b-b0)*256 + hf*64)*HW + hwb + px;
  #pragma unroll
  for (int sl=0; sl<8; sl++){
    u32 wds[4];
    #pragma unroll
    for (int q2=0;q2<4;q2++){
      float a0 = bf2f(yp[(size_t)(sl*8+q2*2      )*HW]);
      float a1 = bf2f(yp[(size_t)(sl*8+q2*2+1    )*HW]);
      float g0 = bf2f(yp[(size_t)(sl*8+q2*2+128  )*HW]);
      float g1 = bf2f(yp[(size_t)(sl*8+q2*2+1+128)*HW]);
      wds[q2] = pk2(gelu_exact(a0)*g0, gelu_exact(a1)*g1);
    }
    int s = hf*8 + sl;
    lsX[px*16 + (s ^ (px&15))] = make_uint4(wds[0],wds[1],wds[2],wds[3]);
  }
  __syncthreads();
  int w4 = tid>>6, l = tid&63, g = l>>4, c15 = l&15;
  f32x4 acc[2][4];
  #pragma unroll
  for (int pp=0;pp<2;pp++)
    #pragma unroll
    for (int po=0;po<4;po++) acc[pp][po] = (f32x4){0.f,0.f,0.f,0.f};
  #pragma unroll
  for (int kk=0; kk<4; kk++){
    v8s wf[4], xf[2];
    #pragma unroll
    for (int po=0;po<4;po++){ int row = po*16 + c15; wf[po] = as8(lsW[row*16 + ((kk*4+g) ^ (row&15))]); }
    #pragma unroll
    for (int pp=0;pp<2;pp++){ int row = w4*32 + pp*16 + c15; xf[pp] = as8(lsX[row*16 + ((kk*4+g) ^ (row&15))]); }
    #pragma unroll
    for (int pp=0;pp<2;pp++)
      #pragma unroll
      for (int po=0;po<4;po++)
        acc[pp][po] = __builtin_amdgcn_mfma_f32_16x16x32_bf16(wf[po], xf[pp], acc[pp][po], 0,0,0);
  }
  size_t obase = (size_t)b*64*HW + hwb + w4*32;
  #pragma unroll
  for (int po=0;po<4;po++)
    #pragma unroll
    for (int j=0;j<4;j++){
      int oc = po*16 + g*4 + j;
      float* dp = out + obase + (size_t)oc*HW + c15;
      #pragma unroll
      for (int pp=0;pp<2;pp++) dp[pp*16] = dp[pp*16] + acc[pp][po][j];
    }
}

// ================= depthwise 3x3, 8px/thread, vectorized =================
__global__ __launch_bounds__(256) void k_dw8(
    const u16* __restrict__ src, const float* __restrict__ wgt, int c0,
    u16* __restrict__ dst, int cmask, int lg, int dstCd, int dstOff)
{
  int t = blockIdx.x*256 + threadIdx.x;
  int w8 = (t & 31)*8, h = (t>>5) & 255;
  int plane = t >> 13;
  int c = plane & cmask, b = plane >> lg;
  const u16* sp = src + (size_t)plane*HW;
  const float* w9 = wgt + (size_t)(c0+c)*9;
  float acc[8] = {0,0,0,0,0,0,0,0};
  #pragma unroll
  for (int r=0;r<3;r++){
    int hh = h + r - 1;
    if (hh < 0 || hh > 255) continue;
    const u16* rp = sp + hh*256 + w8;
    uint4 u = *(const uint4*)rp;
    float vm[10];
    vm[0] = (w8 > 0) ? bf2f(rp[-1]) : 0.f;
    vm[1]=bf2f((u16)(u.x&0xffff)); vm[2]=bf2f((u16)(u.x>>16));
    vm[3]=bf2f((u16)(u.y&0xffff)); vm[4]=bf2f((u16)(u.y>>16));
    vm[5]=bf2f((u16)(u.z&0xffff)); vm[6]=bf2f((u16)(u.z>>16));
    vm[7]=bf2f((u16)(u.w&0xffff)); vm[8]=bf2f((u16)(u.w>>16));
    vm[9] = (w8 < 248) ? bf2f(rp[8]) : 0.f;
    float wa = w9[r*3], wb = w9[r*3+1], wc = w9[r*3+2];
    #pragma unroll
    for (int j=0;j<8;j++) acc[j] += vm[j]*wa + vm[j+1]*wb + vm[j+2]*wc;
  }
  uint4 pkv;
  pkv.x = pk2(acc[0],acc[1]); pkv.y = pk2(acc[2],acc[3]);
  pkv.z = pk2(acc[4],acc[5]); pkv.w = pk2(acc[6],acc[7]);
  *(uint4*)(dst + ((size_t)(b*dstCd + dstOff + c))*HW + h*256 + w8) = pkv;
}

// ================= patch circular conv helpers =================
__device__ __forceinline__ void load_patch_bf(const u16* p, float v[8][8]){
  #pragma unroll
  for (int r=0;r<8;r++){
    uint4 u = *(const uint4*)(p + (size_t)r*256);
    v[r][0]=bf2f((u16)(u.x&0xffff)); v[r][1]=bf2f((u16)(u.x>>16));
    v[r][2]=bf2f((u16)(u.y&0xffff)); v[r][3]=bf2f((u16)(u.y>>16));
    v[r][4]=bf2f((u16)(u.z&0xffff)); v[r][5]=bf2f((u16)(u.z>>16));
    v[r][6]=bf2f((u16)(u.w&0xffff)); v[r][7]=bf2f((u16)(u.w>>16));
  }
}

__device__ __forceinline__ void circ_store_bf(const float q[8][8], const float k[8][8], u16* op){
  #pragma unroll
  for (int i=0;i<8;i++){
    float o[8] = {0,0,0,0,0,0,0,0};
    #pragma unroll
    for (int u=0;u<8;u++){
      #pragma unroll
      for (int v=0;v<8;v++){
        float qq = q[u][v];
        #pragma unroll
        for (int j=0;j<8;j++) o[j] += qq * k[(i-u)&7][(j-v)&7];
      }
    }
    uint4 pk;
    pk.x = pk2(o[0],o[1]); pk.y = pk2(o[2],o[3]);
    pk.z = pk2(o[4],o[5]); pk.w = pk2(o[6],o[7]);
    *(uint4*)(op + (size_t)i*256) = pk;
  }
}

// streaming dw3x3 of an 8x8 patch; halo cols via shfl from neighbor lanes
__device__ __forceinline__ void dws(const u16* __restrict__ plane, const float* __restrict__ w9,
                                    int h0, int w0, int px, int tid, float out[8][8])
{
  #pragma unroll
  for (int i=0;i<8;i++)
    #pragma unroll
    for (int j=0;j<8;j++) out[i][j] = 0.f;
  #pragma unroll
  for (int r=0;r<10;r++){
    int hh = h0 - 1 + r;
    float e[8];
    if (hh >= 0 && hh < 256){
      uint4 u = *(const uint4*)(plane + hh*256 + w0);
      e[0]=bf2f((u16)(u.x&0xffff)); e[1]=bf2f((u16)(u.x>>16));
      e[2]=bf2f((u16)(u.y&0xffff)); e[3]=bf2f((u16)(u.y>>16));
      e[4]=bf2f((u16)(u.z&0xffff)); e[5]=bf2f((u16)(u.z>>16));
      e[6]=bf2f((u16)(u.w&0xffff)); e[7]=bf2f((u16)(u.w>>16));
    } else {
      #pragma unroll
      for (int j=0;j<8;j++) e[j] = 0.f;
    }
    float sL = __shfl(e[7], (tid-1)&63);
    float sR = __shfl(e[0], (tid+1)&63);
    float vm[10];
    vm[0] = (px == 0) ? 0.f : sL;
    #pragma unroll
    for (int j=0;j<8;j++) vm[j+1] = e[j];
    vm[9] = (px == 31) ? 0.f : sR;
    #pragma unroll
    for (int dy=0; dy<3; dy++){
      int i = r - dy;
      if (i < 0 || i > 7) continue;
      float wa = w9[dy*3], wb = w9[dy*3+1], wc = w9[dy*3+2];
      #pragma unroll
      for (int j=0;j<8;j++) out[i][j] += vm[j]*wa + vm[j+1]*wb + vm[j+2]*wc;
    }
  }
}

// fused dw3x3(q), dw3x3(k) + per-patch circular conv
__global__ __launch_bounds__(64) void k_circqk(
    const u16* __restrict__ bq, const u16* __restrict__ bk,
    const float* __restrict__ dwq, const float* __restrict__ dwk, int c0,
    u16* __restrict__ oraw, int oc0)
{
  int tid = threadIdx.x;
  int px = tid & 31, py = blockIdx.x*2 + (tid>>5);
  int c = blockIdx.y, b = blockIdx.z;
  int h0 = py*8, w0 = px*8;
  float qv[8][8], kv[8][8];
  dws(bq + ((size_t)(b*64+c))*HW, dwq + (size_t)(c0+c)*9, h0, w0, px, tid, qv);
  dws(bk + ((size_t)(b*64+c))*HW, dwk + (size_t)(c0+c)*9, h0, w0, px, tid, kv);
  circ_store_bf(qv, kv, oraw + ((size_t)(b*128 + oc0 + c))*HW + (size_t)h0*256 + w0);
}

// DFFN spectral circular conv, in-place on (2,256,HW) half
__global__ __launch_bounds__(64) void k_circg(
    u16* __restrict__ y, const float* __restrict__ g)
{
  int tid = threadIdx.x;
  int px = tid & 31, py = blockIdx.x*2 + (tid>>5);
  int c = blockIdx.y, b = blockIdx.z;
  u16* p = y + ((size_t)(b*256+c))*HW + (size_t)py*8*256 + (size_t)px*8;
  float yv[8][8], kv[8][8];
  load_patch_bf(p, yv);
  const float* gp = g + (size_t)c*64;
  #pragma unroll
  for (int r=0;r<8;r++)
    #pragma unroll
    for (int j=0;j<8;j++) kv[r][j] = gp[r*8+j];
  circ_store_bf(yv, kv, p);
}

extern "C" void kernel_launch(void* const* d_in, const int* in_sizes, int n_in,
                              void* d_out, int out_size, void* d_ws, size_t ws_size,
                              hipStream_t stream)
{
  const float* x       = (const float*)d_in[0];
  const float* evt     = (const float*)d_in[1];
  const float* ln1i_w  = (const float*)d_in[2];
  const float* ln1i_b  = (const float*)d_in[3];
  const float* ln1e_w  = (const float*)d_in[4];
  const float* ln1e_b  = (const float*)d_in[5];
  const float* w_q     = (const float*)d_in[6];
  const float* dw_q    = (const float*)d_in[7];
  const float* w_kv    = (const float*)d_in[8];
  const float* dw_kv   = (const float*)d_in[9];
  const float* lnA_w   = (const float*)d_in[10];
  const float* lnA_b   = (const float*)d_in[11];
  const float* w_po_at = (const float*)d_in[12];
  const float* ln2_w   = (const float*)d_in[13];
  const float* ln2_b   = (const float*)d_in[14];
  const float* w_pi    = (const float*)d_in[15];
  const float* fft_par = (const float*)d_in[16];
  const float* dw_ffn  = (const float*)d_in[17];
  const float* w_poffn = (const float*)d_in[18];
  float* out = (float*)d_out;

  char* ws = (char*)d_ws;
  const size_t MiB = 1048576ull;
  u16*   P1   = (u16*)(ws);                    // 32 MiB  (B,64,HW) scratch
  u16*   ORAW = (u16*)(ws + 32*MiB);           // 64 MiB  (B,128,HW)
  u16*   P2   = (u16*)(ws + 96*MiB);           // 32 MiB
  u16*   VBUF = (u16*)(ws + 96*MiB);           // 64 MiB  (B,128,HW) — after P2 dead
  float2* SX  = (float2*)(ws + 144*MiB);       // 2 MiB
  float2* SE  = (float2*)(ws + 146*MiB);       // 2 MiB
  float2* S2  = (float2*)(ws);                 // 2 MiB — after P1 dead
  u16*   Y0   = (u16*)(ws + 8*MiB);            // 64 MiB  (2,256,HW) half
  u16*   Y3   = (u16*)(ws + 72*MiB);           // 64 MiB
  char* sm = ws + 160*MiB;
  float* G    = (float*)(sm);                  // 64 KiB
  u16* WQF    = (u16*)(sm + 65536);            // 16 KiB
  u16* WKVF   = (u16*)(sm + 81920);            // 32 KiB
  u16* WPIF   = (u16*)(sm + 114688);           // 32 KiB
  u16* WPAF   = (u16*)(sm + 147456);           // 16 KiB
  u16* WPFF   = (u16*)(sm + 163840);           // 16 KiB
  float* AQ   = (float*)(sm + 180224);
  float* BQ   = (float*)(sm + 180736);
  float* AKV  = (float*)(sm + 181248);
  float* BKV  = (float*)(sm + 182272);
  float* API  = (float*)(sm + 183296);
  float* BPI  = (float*)(sm + 184320);

  dim3 blk256(256), blk64(64);

  k_prep<<<69, blk256, 0, stream>>>(fft_par, G,
      w_q, ln1i_w, ln1i_b, WQF, AQ, BQ,
      w_kv, ln1e_w, ln1e_b, WKVF, AKV, BKV,
      w_pi, ln2_w, ln2_b, WPIF, API, BPI,
      w_po_at, WPAF, w_poffn, WPFF);

  k_stats<<<dim3(1024,2), blk256, 0, stream>>>(x, SX, evt, SE);

  // ---- attention q,k chunks ----
  for (int i=0;i<2;i++){
    GA qa = {x,   SX, WQF,  AQ,  BQ,  P1, 64*i, 0, 64, 0, 0};
    GA ka = {evt, SE, WKVF, AKV, BKV, P2, 64*i, 0, 64, 0, 0};
    k_gemm64<<<dim3(1024,2,1), blk256, 0, stream>>>(qa, ka);
    k_circqk<<<dim3(16,64,4), blk64, 0, stream>>>(P1, P2, dw_q, dw_kv, 64*i, ORAW, 64*i);
  }
  // ---- v chunks ----
  for (int i=0;i<2;i++){
    GA va = {evt, SE, WKVF, AKV, BKV, P1, 128+64*i, 0, 64, 0, 0};
    k_gemm64<<<dim3(1024,1,1), blk256, 0, stream>>>(va, va);
    k_dw8<<<8192, blk256, 0, stream>>>(P1, dw_kv, 128+64*i, VBUF, 63, 6, 128, 64*i);
  }
  // ---- attn epilogue -> d_out ----
  k_gemm_attn<<<2048, blk256, 0, stream>>>(x, ORAW, VBUF, lnA_w, lnA_b, WPAF, out);

  // ---- ln2 stats on x2 ----
  k_stats<<<dim3(1024,1), blk256, 0, stream>>>(out, S2, out, S2);

  // ---- DFFN in two batch-halves ----
  for (int h=0;h<2;h++){
    GA pa = {out, S2, WPIF, API, BPI, Y0, 0, 0, 256, 2*h, h*131072};
    k_gemm64<<<dim3(512,1,4), blk256, 0, stream>>>(pa, pa);
    k_circg<<<dim3(16,256,2), blk64, 0, stream>>>(Y0, G);
    k_dw8<<<16384, blk256, 0, stream>>>(Y0, dw_ffn, 0, Y3, 255, 8, 256, 0);
    k_gemm_ffn<<<1024, blk256, 0, stream>>>(Y3, WPFF, out, h*131072, 2*h);
  }
}

// Round 5
// 698.056 us; speedup vs baseline: 5.4327x; 2.0119x over previous
//
#include <hip/hip_runtime.h>

#define HW 65536          // 256*256
#define NPOS 262144       // B(4) * HW

typedef unsigned int   u32;
typedef unsigned short u16;
typedef __attribute__((ext_vector_type(8))) short v8s;
typedef __attribute__((ext_vector_type(4))) float f32x4;

__device__ __forceinline__ float bf2f(u16 h){
  union { u32 u; float f; } c; c.u = ((u32)h) << 16; return c.f;
}
__device__ __forceinline__ u16 f2bf(float f){
  union { u32 u; float f; } c; c.f = f;
  u32 r = c.u + 0x7fffu + ((c.u >> 16) & 1u);
  return (u16)(r >> 16);
}
__device__ __forceinline__ u32 pk2(float a, float b){
  return (u32)f2bf(a) | ((u32)f2bf(b) << 16);
}
__device__ __forceinline__ v8s as8(uint4 u){
  union { uint4 a; v8s b; } c; c.a = u; return c.b;
}
__device__ __forceinline__ float gelu_exact(float x){
  return 0.5f*x*(1.0f+erff(x*0.70710678118654752f));
}

// ================= prep: spectral kernel g + LN-folded bf16 weights =================
__device__ void fold_w(const float* __restrict__ W, int rows,
                       const float* __restrict__ lw, const float* __restrict__ lb,
                       u16* __restrict__ Wf, float* __restrict__ A, float* __restrict__ B){
  int tid = threadIdx.x;
  for (int e = tid; e < rows*64; e += 256) Wf[e] = f2bf(lw[e & 63] * W[e]);
  for (int r = tid; r < rows; r += 256){
    float a = 0.f, b2 = 0.f;
    for (int c = 0; c < 64; c++){ float w = W[r*64+c]; a += lw[c]*w; b2 += lb[c]*w; }
    A[r] = a; B[r] = b2;
  }
}

__global__ void k_prep(const float* __restrict__ M, float* __restrict__ g,
    const float* wq,  const float* l1iw, const float* l1ib, u16* wqf,  float* aq,  float* bq,
    const float* wkv, const float* l1ew, const float* l1eb, u16* wkvf, float* akv, float* bkv,
    const float* wpi, const float* l2w,  const float* l2b,  u16* wpif, float* api, float* bpi,
    const float* wpa, u16* wpaf, const float* wpf, u16* wpff)
{
  int blk = blockIdx.x, tid = threadIdx.x;
  if (blk < 64){
    int t = blk*256 + tid;           // < 256*64
    int c = t >> 6, uv = t & 63, u = uv >> 3, v = uv & 7;
    const float* mc = M + c*40;
    const float ctab[8] = {1.f, 0.70710678118654752f, 0.f, -0.70710678118654752f,
                           -1.f, -0.70710678118654752f, 0.f, 0.70710678118654752f};
    float acc = 0.f;
    for (int k1=0;k1<8;k1++)
      for (int k2=0;k2<8;k2++){
        float s = (k2<=4) ? mc[k1*5+k2] : mc[(((8-k1)&7)*5) + (8-k2)];
        acc += s * ctab[(k1*u + k2*v)&7];
      }
    g[t] = acc * (1.f/64.f);
  } else if (blk == 64){ fold_w(wq, 128, l1iw, l1ib, wqf, aq, bq); }
  else if (blk == 65){ fold_w(wkv, 256, l1ew, l1eb, wkvf, akv, bkv); }
  else if (blk == 66){ fold_w(wpi, 256, l2w, l2b, wpif, api, bpi); }
  else if (blk == 67){ for (int e=tid; e<64*128; e+=256) wpaf[e] = f2bf(wpa[e]); }
  else               { for (int e=tid; e<64*128; e+=256) wpff[e] = f2bf(wpf[e]); }
}

// ================= per-pixel LN stats (mu, inv) over 64 channels =================
__global__ __launch_bounds__(256) void k_stats(
    const float* __restrict__ s0, float2* __restrict__ d0,
    const float* __restrict__ s1, float2* __restrict__ d1)
{
  const float* src = blockIdx.y ? s1 : s0;
  float2* dst = blockIdx.y ? d1 : d0;
  int p = blockIdx.x*256 + threadIdx.x;
  int b = p >> 16, hw = p & 65535;
  const float* sp = src + (size_t)b*64*HW + hw;
  float s = 0.f, q = 0.f;
  #pragma unroll
  for (int c=0;c<64;c++){ float e = sp[(size_t)c*HW]; s += e; q += e*e; }
  float mu = s*(1.f/64.f);
  float var = q*(1.f/64.f) - mu*mu;
  dst[p] = make_float2(mu, rsqrtf(fmaxf(var,0.f)+1e-5f));
}

// ================= K=64 GEMM with folded LN: dst[o] = inv*(acc - mu*A[o]) + B[o] =================
struct GA {
  const float* src; const float2* st; const u16* Wf; const float* Af; const float* Bf;
  u16* dst; int o0; int dstOff; int Cd; int b0; int pxbase;
};

__global__ __launch_bounds__(256) void k_gemm64(GA a0, GA a1){
  GA a = (blockIdx.y == 0) ? a0 : a1;
  int o0 = a.o0 + 64*blockIdx.z;
  int dstOff = a.dstOff + 64*blockIdx.z;
  __shared__ uint4 lsX[256*8];   // 32KB
  __shared__ uint4 lsW[64*8];    // 8KB
  int tid = threadIdx.x;
  int p0 = a.pxbase + blockIdx.x*256;
  int b = p0 >> 16, hwb = p0 & 65535;
  {
    const uint4* wsrc = (const uint4*)(a.Wf + (size_t)o0*64);
    #pragma unroll
    for (int i=0;i<2;i++){
      int idx = i*256 + tid, row = idx>>3, s = idx&7;
      lsW[row*8 + (s ^ (row&7))] = wsrc[idx];
    }
  }
  {
    const float* sp = a.src + (size_t)b*64*HW + hwb + tid;
    uint4* xrow = lsX + tid*8;
    #pragma unroll
    for (int sl=0; sl<8; sl++){
      float e0=sp[(size_t)(sl*8+0)*HW], e1=sp[(size_t)(sl*8+1)*HW];
      float e2=sp[(size_t)(sl*8+2)*HW], e3=sp[(size_t)(sl*8+3)*HW];
      float e4=sp[(size_t)(sl*8+4)*HW], e5=sp[(size_t)(sl*8+5)*HW];
      float e6=sp[(size_t)(sl*8+6)*HW], e7=sp[(size_t)(sl*8+7)*HW];
      uint4 pkv; pkv.x=pk2(e0,e1); pkv.y=pk2(e2,e3); pkv.z=pk2(e4,e5); pkv.w=pk2(e6,e7);
      xrow[sl ^ (tid&7)] = pkv;
    }
  }
  __syncthreads();
  int w = tid>>6, l = tid&63, g = l>>4, c15 = l&15;
  f32x4 acc[4][4];
  #pragma unroll
  for (int pp=0;pp<4;pp++)
    #pragma unroll
    for (int po=0;po<4;po++) acc[pp][po] = (f32x4){0.f,0.f,0.f,0.f};
  #pragma unroll
  for (int kk=0; kk<2; kk++){
    v8s wf[4], xf[4];
    #pragma unroll
    for (int po=0;po<4;po++){ int row = po*16 + c15; wf[po] = as8(lsW[row*8 + ((kk*4+g) ^ (row&7))]); }
    #pragma unroll
    for (int pp=0;pp<4;pp++){ int row = w*64 + pp*16 + c15; xf[pp] = as8(lsX[row*8 + ((kk*4+g) ^ (row&7))]); }
    #pragma unroll
    for (int pp=0;pp<4;pp++)
      #pragma unroll
      for (int po=0;po<4;po++)
        acc[pp][po] = __builtin_amdgcn_mfma_f32_16x16x32_bf16(wf[po], xf[pp], acc[pp][po], 0,0,0);
  }
  float2 stv[4];
  #pragma unroll
  for (int pp=0;pp<4;pp++) stv[pp] = a.st[p0 + w*64 + pp*16 + c15];
  size_t obase = ((size_t)(b - a.b0)*a.Cd + dstOff)*HW + hwb + w*64;
  #pragma unroll
  for (int po=0;po<4;po++)
    #pragma unroll
    for (int j=0;j<4;j++){
      int oc = po*16 + g*4 + j;
      float Ao = a.Af[o0+oc], Bo = a.Bf[o0+oc];
      u16* dp = a.dst + obase + (size_t)oc*HW + c15;
      #pragma unroll
      for (int pp=0;pp<4;pp++)
        dp[pp*16] = f2bf(stv[pp].y*(acc[pp][po][j] - stv[pp].x*Ao) + Bo);
    }
}

// ================= attn epilogue GEMM (K=128): out = x + Wpo * (v .* LN128(oraw)) =================
__global__ __launch_bounds__(256) void k_gemm_attn(
    const float* __restrict__ x, const u16* __restrict__ oraw, const u16* __restrict__ vb,
    const float* __restrict__ lnw, const float* __restrict__ lnb,
    const u16* __restrict__ Wf, float* __restrict__ out)
{
  __shared__ uint4 lsX[128*16];  // 32KB
  __shared__ uint4 lsW[64*16];   // 16KB
  __shared__ float2 sPart[256];
  __shared__ float2 sStat[128];
  int tid = threadIdx.x;
  int p0 = blockIdx.x*128;
  int b = p0 >> 16, hwb = p0 & 65535;
  int px = tid & 127, hf = tid >> 7;
  {
    const uint4* wsrc = (const uint4*)Wf;
    #pragma unroll
    for (int i=0;i<4;i++){
      int idx = i*256 + tid, row = idx>>4, s = idx&15;
      lsW[row*16 + (s ^ (row&15))] = wsrc[idx];
    }
  }
  const u16* op_ = oraw + ((size_t)b*128 + hf*64)*HW + hwb + px;
  float sum = 0.f, ssq = 0.f;
  #pragma unroll
  for (int sl=0; sl<8; sl++){
    u32 wds[4];
    #pragma unroll
    for (int q2=0;q2<4;q2++){
      u16 lo = op_[(size_t)(sl*8+q2*2  )*HW];
      u16 hi = op_[(size_t)(sl*8+q2*2+1)*HW];
      float fl = bf2f(lo), fh = bf2f(hi);
      sum += fl + fh; ssq += fl*fl + fh*fh;
      wds[q2] = (u32)lo | ((u32)hi << 16);
    }
    int s = hf*8 + sl;
    lsX[px*16 + (s ^ (px&15))] = make_uint4(wds[0],wds[1],wds[2],wds[3]);
  }
  sPart[tid] = make_float2(sum, ssq);
  __syncthreads();
  if (tid < 128){
    float2 A = sPart[tid], B = sPart[tid+128];
    float s = A.x + B.x, q = A.y + B.y;
    float mu = s*(1.f/128.f);
    float var = q*(1.f/128.f) - mu*mu;
    sStat[tid] = make_float2(mu, rsqrtf(fmaxf(var,0.f)+1e-5f));
  }
  __syncthreads();
  float2 st = sStat[px];
  const u16* vp = vb + ((size_t)b*128 + hf*64)*HW + hwb + px;
  #pragma unroll
  for (int sl=0; sl<8; sl++){
    int s = hf*8 + sl;
    int li = px*16 + (s ^ (px&15));
    uint4 raw = lsX[li];
    u32 wds[4] = {raw.x, raw.y, raw.z, raw.w};
    u32 ow[4];
    #pragma unroll
    for (int q2=0;q2<4;q2++){
      int ch = hf*64 + sl*8 + q2*2;
      float e0 = bf2f((u16)(wds[q2]&0xffff)), e1 = bf2f((u16)(wds[q2]>>16));
      float v0 = bf2f(vp[(size_t)(sl*8+q2*2  )*HW]);
      float v1 = bf2f(vp[(size_t)(sl*8+q2*2+1)*HW]);
      float r0 = ((e0-st.x)*st.y*lnw[ch  ] + lnb[ch  ])*v0;
      float r1 = ((e1-st.x)*st.y*lnw[ch+1] + lnb[ch+1])*v1;
      ow[q2] = pk2(r0, r1);
    }
    lsX[li] = make_uint4(ow[0],ow[1],ow[2],ow[3]);
  }
  __syncthreads();
  int w4 = tid>>6, l = tid&63, g = l>>4, c15 = l&15;
  f32x4 acc[2][4];
  #pragma unroll
  for (int pp=0;pp<2;pp++)
    #pragma unroll
    for (int po=0;po<4;po++) acc[pp][po] = (f32x4){0.f,0.f,0.f,0.f};
  #pragma unroll
  for (int kk=0; kk<4; kk++){
    v8s wf[4], xf[2];
    #pragma unroll
    for (int po=0;po<4;po++){ int row = po*16 + c15; wf[po] = as8(lsW[row*16 + ((kk*4+g) ^ (row&15))]); }
    #pragma unroll
    for (int pp=0;pp<2;pp++){ int row = w4*32 + pp*16 + c15; xf[pp] = as8(lsX[row*16 + ((kk*4+g) ^ (row&15))]); }
    #pragma unroll
    for (int pp=0;pp<2;pp++)
      #pragma unroll
      for (int po=0;po<4;po++)
        acc[pp][po] = __builtin_amdgcn_mfma_f32_16x16x32_bf16(wf[po], xf[pp], acc[pp][po], 0,0,0);
  }
  size_t obase = (size_t)b*64*HW + hwb + w4*32;
  #pragma unroll
  for (int po=0;po<4;po++)
    #pragma unroll
    for (int j=0;j<4;j++){
      int oc = po*16 + g*4 + j;
      const float* xs = x + obase + (size_t)oc*HW + c15;
      float* dp = out + obase + (size_t)oc*HW + c15;
      #pragma unroll
      for (int pp=0;pp<2;pp++) dp[pp*16] = xs[pp*16] + acc[pp][po][j];
    }
}

// ================= ffn epilogue GEMM (K=128): out += Wpo * (gelu(y[:128]) .* y[128:]) =================
__global__ __launch_bounds__(256) void k_gemm_ffn(
    const u16* __restrict__ y3, const u16* __restrict__ Wf, float* __restrict__ out,
    int pxbase, int b0)
{
  __shared__ uint4 lsX[128*16];
  __shared__ uint4 lsW[64*16];
  int tid = threadIdx.x;
  int p0 = pxbase + blockIdx.x*128;
  int b = p0 >> 16, hwb = p0 & 65535;
  int px = tid & 127, hf = tid >> 7;
  {
    const uint4* wsrc = (const uint4*)Wf;
    #pragma unroll
    for (int i=0;i<4;i++){
      int idx = i*256 + tid, row = idx>>4, s = idx&15;
      lsW[row*16 + (s ^ (row&15))] = wsrc[idx];
    }
  }
  const u16* yp = y3 + ((size_t)(b-b0)*256 + hf*64)*HW + hwb + px;
  #pragma unroll
  for (int sl=0; sl<8; sl++){
    u32 wds[4];
    #pragma unroll
    for (int q2=0;q2<4;q2++){
      float a0 = bf2f(yp[(size_t)(sl*8+q2*2      )*HW]);
      float a1 = bf2f(yp[(size_t)(sl*8+q2*2+1    )*HW]);
      float g0 = bf2f(yp[(size_t)(sl*8+q2*2+128  )*HW]);
      float g1 = bf2f(yp[(size_t)(sl*8+q2*2+1+128)*HW]);
      wds[q2] = pk2(gelu_exact(a0)*g0, gelu_exact(a1)*g1);
    }
    int s = hf*8 + sl;
    lsX[px*16 + (s ^ (px&15))] = make_uint4(wds[0],wds[1],wds[2],wds[3]);
  }
  __syncthreads();
  int w4 = tid>>6, l = tid&63, g = l>>4, c15 = l&15;
  f32x4 acc[2][4];
  #pragma unroll
  for (int pp=0;pp<2;pp++)
    #pragma unroll
    for (int po=0;po<4;po++) acc[pp][po] = (f32x4){0.f,0.f,0.f,0.f};
  #pragma unroll
  for (int kk=0; kk<4; kk++){
    v8s wf[4], xf[2];
    #pragma unroll
    for (int po=0;po<4;po++){ int row = po*16 + c15; wf[po] = as8(lsW[row*16 + ((kk*4+g) ^ (row&15))]); }
    #pragma unroll
    for (int pp=0;pp<2;pp++){ int row = w4*32 + pp*16 + c15; xf[pp] = as8(lsX[row*16 + ((kk*4+g) ^ (row&15))]); }
    #pragma unroll
    for (int pp=0;pp<2;pp++)
      #pragma unroll
      for (int po=0;po<4;po++)
        acc[pp][po] = __builtin_amdgcn_mfma_f32_16x16x32_bf16(wf[po], xf[pp], acc[pp][po], 0,0,0);
  }
  size_t obase = (size_t)b*64*HW + hwb + w4*32;
  #pragma unroll
  for (int po=0;po<4;po++)
    #pragma unroll
    for (int j=0;j<4;j++){
      int oc = po*16 + g*4 + j;
      float* dp = out + obase + (size_t)oc*HW + c15;
      #pragma unroll
      for (int pp=0;pp<2;pp++) dp[pp*16] = dp[pp*16] + acc[pp][po][j];
    }
}

// ================= depthwise 3x3, 8px/thread, vectorized =================
__global__ __launch_bounds__(256) void k_dw8(
    const u16* __restrict__ src, const float* __restrict__ wgt, int c0,
    u16* __restrict__ dst, int cmask, int lg, int dstCd, int dstOff)
{
  int t = blockIdx.x*256 + threadIdx.x;
  int w8 = (t & 31)*8, h = (t>>5) & 255;
  int plane = t >> 13;
  int c = plane & cmask, b = plane >> lg;
  const u16* sp = src + (size_t)plane*HW;
  const float* w9 = wgt + (size_t)(c0+c)*9;
  float acc[8] = {0,0,0,0,0,0,0,0};
  #pragma unroll
  for (int r=0;r<3;r++){
    int hh = h + r - 1;
    if (hh < 0 || hh > 255) continue;
    const u16* rp = sp + hh*256 + w8;
    uint4 u = *(const uint4*)rp;
    float vm[10];
    vm[0] = (w8 > 0) ? bf2f(rp[-1]) : 0.f;
    vm[1]=bf2f((u16)(u.x&0xffff)); vm[2]=bf2f((u16)(u.x>>16));
    vm[3]=bf2f((u16)(u.y&0xffff)); vm[4]=bf2f((u16)(u.y>>16));
    vm[5]=bf2f((u16)(u.z&0xffff)); vm[6]=bf2f((u16)(u.z>>16));
    vm[7]=bf2f((u16)(u.w&0xffff)); vm[8]=bf2f((u16)(u.w>>16));
    vm[9] = (w8 < 248) ? bf2f(rp[8]) : 0.f;
    float wa = w9[r*3], wb = w9[r*3+1], wc = w9[r*3+2];
    #pragma unroll
    for (int j=0;j<8;j++) acc[j] += vm[j]*wa + vm[j+1]*wb + vm[j+2]*wc;
  }
  uint4 pkv;
  pkv.x = pk2(acc[0],acc[1]); pkv.y = pk2(acc[2],acc[3]);
  pkv.z = pk2(acc[4],acc[5]); pkv.w = pk2(acc[6],acc[7]);
  *(uint4*)(dst + ((size_t)(b*dstCd + dstOff + c))*HW + h*256 + w8) = pkv;
}

// ================= dw3x3 of one row-of-8, writing f32 to an LDS row =================
__device__ __forceinline__ void dw_row8_lds(const u16* __restrict__ plane, const float* __restrict__ w9,
                                            int h, int w8, float* __restrict__ dstLds)
{
  float acc[8] = {0,0,0,0,0,0,0,0};
  #pragma unroll
  for (int r=0;r<3;r++){
    int hh = h + r - 1;
    if (hh < 0 || hh > 255) continue;
    const u16* rp = plane + hh*256 + w8;
    uint4 u = *(const uint4*)rp;
    float vm[10];
    vm[0] = (w8 > 0) ? bf2f(rp[-1]) : 0.f;
    vm[1]=bf2f((u16)(u.x&0xffff)); vm[2]=bf2f((u16)(u.x>>16));
    vm[3]=bf2f((u16)(u.y&0xffff)); vm[4]=bf2f((u16)(u.y>>16));
    vm[5]=bf2f((u16)(u.z&0xffff)); vm[6]=bf2f((u16)(u.z>>16));
    vm[7]=bf2f((u16)(u.w&0xffff)); vm[8]=bf2f((u16)(u.w>>16));
    vm[9] = (w8 < 248) ? bf2f(rp[8]) : 0.f;
    float wa = w9[r*3], wb = w9[r*3+1], wc = w9[r*3+2];
    #pragma unroll
    for (int j=0;j<8;j++) acc[j] += vm[j]*wa + vm[j+1]*wb + vm[j+2]*wc;
  }
  #pragma unroll
  for (int j=0;j<8;j++) dstLds[j] = acc[j];
}

// ================= fused dw(q), dw(k) + per-patch 8x8 circular conv, LDS-staged =================
// block 256 = 32 patches x 8 rows; grid (32, 64, 4)
__global__ __launch_bounds__(256) void k_circqk2(
    const u16* __restrict__ bq, const u16* __restrict__ bk,
    const float* __restrict__ dwq, const float* __restrict__ dwk, int c0,
    u16* __restrict__ oraw, int oc0)
{
  __shared__ float qd[8][288];   // [row][patch*9 + v], stride 9 => conflict-free
  __shared__ float kd[8][288];
  int tid = threadIdx.x;
  int p = tid & 31, i = tid >> 5;
  int c = blockIdx.y, b = blockIdx.z;
  int h0 = blockIdx.x*8;
  const u16* qp = bq + ((size_t)(b*64+c))*HW;
  const u16* kp = bk + ((size_t)(b*64+c))*HW;
  dw_row8_lds(qp, dwq + (size_t)(c0+c)*9, h0+i, p*8, &qd[i][p*9]);
  dw_row8_lds(kp, dwk + (size_t)(c0+c)*9, h0+i, p*8, &kd[i][p*9]);
  __syncthreads();
  float o[8] = {0,0,0,0,0,0,0,0};
  #pragma unroll
  for (int u=0;u<8;u++){
    float qv[8], kr[8];
    #pragma unroll
    for (int v=0;v<8;v++) qv[v] = qd[u][p*9+v];
    const float* krow = &kd[(i-u)&7][p*9];
    #pragma unroll
    for (int e=0;e<8;e++) kr[e] = krow[e];
    #pragma unroll
    for (int v=0;v<8;v++){
      float qq = qv[v];
      #pragma unroll
      for (int j=0;j<8;j++) o[j] += qq * kr[(j-v)&7];
    }
  }
  u16* op = oraw + ((size_t)(b*128 + oc0 + c))*HW + (size_t)(h0+i)*256 + p*8;
  uint4 pkv;
  pkv.x = pk2(o[0],o[1]); pkv.y = pk2(o[2],o[3]);
  pkv.z = pk2(o[4],o[5]); pkv.w = pk2(o[6],o[7]);
  *(uint4*)op = pkv;
}

// ================= DFFN spectral circular conv (kernel g), LDS-staged, in-place =================
// block 256 = 32 patches x 8 rows; grid (32, 256, 2) per batch-half
__global__ __launch_bounds__(256) void k_circg2(
    u16* __restrict__ y, const float* __restrict__ g)
{
  __shared__ float yd[8][288];
  __shared__ float gs[64];
  int tid = threadIdx.x;
  int p = tid & 31, i = tid >> 5;
  int c = blockIdx.y, b = blockIdx.z;
  int h0 = blockIdx.x*8;
  u16* plane = y + ((size_t)(b*256+c))*HW;
  {
    const u16* rp = plane + (size_t)(h0+i)*256 + p*8;
    uint4 u = *(const uint4*)rp;
    float* dr = &yd[i][p*9];
    dr[0]=bf2f((u16)(u.x&0xffff)); dr[1]=bf2f((u16)(u.x>>16));
    dr[2]=bf2f((u16)(u.y&0xffff)); dr[3]=bf2f((u16)(u.y>>16));
    dr[4]=bf2f((u16)(u.z&0xffff)); dr[5]=bf2f((u16)(u.z>>16));
    dr[6]=bf2f((u16)(u.w&0xffff)); dr[7]=bf2f((u16)(u.w>>16));
  }
  if (tid < 64) gs[tid] = g[(size_t)c*64 + tid];
  __syncthreads();
  float o[8] = {0,0,0,0,0,0,0,0};
  #pragma unroll
  for (int u=0;u<8;u++){
    float yv[8], gr[8];
    #pragma unroll
    for (int v=0;v<8;v++) yv[v] = yd[u][p*9+v];
    const float* grow = &gs[((i-u)&7)*8];
    #pragma unroll
    for (int e=0;e<8;e++) gr[e] = grow[e];
    #pragma unroll
    for (int v=0;v<8;v++){
      float qq = yv[v];
      #pragma unroll
      for (int j=0;j<8;j++) o[j] += qq * gr[(j-v)&7];
    }
  }
  u16* op = plane + (size_t)(h0+i)*256 + p*8;
  uint4 pkv;
  pkv.x = pk2(o[0],o[1]); pkv.y = pk2(o[2],o[3]);
  pkv.z = pk2(o[4],o[5]); pkv.w = pk2(o[6],o[7]);
  *(uint4*)op = pkv;
}

extern "C" void kernel_launch(void* const* d_in, const int* in_sizes, int n_in,
                              void* d_out, int out_size, void* d_ws, size_t ws_size,
                              hipStream_t stream)
{
  const float* x       = (const float*)d_in[0];
  const float* evt     = (const float*)d_in[1];
  const float* ln1i_w  = (const float*)d_in[2];
  const float* ln1i_b  = (const float*)d_in[3];
  const float* ln1e_w  = (const float*)d_in[4];
  const float* ln1e_b  = (const float*)d_in[5];
  const float* w_q     = (const float*)d_in[6];
  const float* dw_q    = (const float*)d_in[7];
  const float* w_kv    = (const float*)d_in[8];
  const float* dw_kv   = (const float*)d_in[9];
  const float* lnA_w   = (const float*)d_in[10];
  const float* lnA_b   = (const float*)d_in[11];
  const float* w_po_at = (const float*)d_in[12];
  const float* ln2_w   = (const float*)d_in[13];
  const float* ln2_b   = (const float*)d_in[14];
  const float* w_pi    = (const float*)d_in[15];
  const float* fft_par = (const float*)d_in[16];
  const float* dw_ffn  = (const float*)d_in[17];
  const float* w_poffn = (const float*)d_in[18];
  float* out = (float*)d_out;

  char* ws = (char*)d_ws;
  const size_t MiB = 1048576ull;
  u16*   P1   = (u16*)(ws);                    // 32 MiB  (B,64,HW) scratch
  u16*   ORAW = (u16*)(ws + 32*MiB);           // 64 MiB  (B,128,HW)
  u16*   P2   = (u16*)(ws + 96*MiB);           // 32 MiB
  u16*   VBUF = (u16*)(ws + 96*MiB);           // 64 MiB  (B,128,HW) — after P2 dead
  float2* SX  = (float2*)(ws + 144*MiB);       // 2 MiB
  float2* SE  = (float2*)(ws + 146*MiB);       // 2 MiB
  float2* S2  = (float2*)(ws);                 // 2 MiB — after P1 dead
  u16*   Y0   = (u16*)(ws + 8*MiB);            // 64 MiB  (2,256,HW) half
  u16*   Y3   = (u16*)(ws + 72*MiB);           // 64 MiB
  char* sm = ws + 160*MiB;
  float* G    = (float*)(sm);                  // 64 KiB
  u16* WQF    = (u16*)(sm + 65536);            // 16 KiB
  u16* WKVF   = (u16*)(sm + 81920);            // 32 KiB
  u16* WPIF   = (u16*)(sm + 114688);           // 32 KiB
  u16* WPAF   = (u16*)(sm + 147456);           // 16 KiB
  u16* WPFF   = (u16*)(sm + 163840);           // 16 KiB
  float* AQ   = (float*)(sm + 180224);
  float* BQ   = (float*)(sm + 180736);
  float* AKV  = (float*)(sm + 181248);
  float* BKV  = (float*)(sm + 182272);
  float* API  = (float*)(sm + 183296);
  float* BPI  = (float*)(sm + 184320);

  dim3 blk256(256);

  k_prep<<<69, blk256, 0, stream>>>(fft_par, G,
      w_q, ln1i_w, ln1i_b, WQF, AQ, BQ,
      w_kv, ln1e_w, ln1e_b, WKVF, AKV, BKV,
      w_pi, ln2_w, ln2_b, WPIF, API, BPI,
      w_po_at, WPAF, w_poffn, WPFF);

  k_stats<<<dim3(1024,2), blk256, 0, stream>>>(x, SX, evt, SE);

  // ---- attention q,k chunks ----
  for (int i=0;i<2;i++){
    GA qa = {x,   SX, WQF,  AQ,  BQ,  P1, 64*i, 0, 64, 0, 0};
    GA ka = {evt, SE, WKVF, AKV, BKV, P2, 64*i, 0, 64, 0, 0};
    k_gemm64<<<dim3(1024,2,1), blk256, 0, stream>>>(qa, ka);
    k_circqk2<<<dim3(32,64,4), blk256, 0, stream>>>(P1, P2, dw_q, dw_kv, 64*i, ORAW, 64*i);
  }
  // ---- v chunks ----
  for (int i=0;i<2;i++){
    GA va = {evt, SE, WKVF, AKV, BKV, P1, 128+64*i, 0, 64, 0, 0};
    k_gemm64<<<dim3(1024,1,1), blk256, 0, stream>>>(va, va);
    k_dw8<<<8192, blk256, 0, stream>>>(P1, dw_kv, 128+64*i, VBUF, 63, 6, 128, 64*i);
  }
  // ---- attn epilogue -> d_out ----
  k_gemm_attn<<<2048, blk256, 0, stream>>>(x, ORAW, VBUF, lnA_w, lnA_b, WPAF, out);

  // ---- ln2 stats on x2 ----
  k_stats<<<dim3(1024,1), blk256, 0, stream>>>(out, S2, out, S2);

  // ---- DFFN in two batch-halves ----
  for (int h=0;h<2;h++){
    GA pa = {out, S2, WPIF, API, BPI, Y0, 0, 0, 256, 2*h, h*131072};
    k_gemm64<<<dim3(512,1,4), blk256, 0, stream>>>(pa, pa);
    k_circg2<<<dim3(32,256,2), blk256, 0, stream>>>(Y0, G);
    k_dw8<<<16384, blk256, 0, stream>>>(Y0, dw_ffn, 0, Y3, 255, 8, 256, 0);
    k_gemm_ffn<<<1024, blk256, 0, stream>>>(Y3, WPFF, out, h*131072, 2*h);
  }
}